// Round 2
// baseline (498.507 us; speedup 1.0000x reference)
//
#include <hip/hip_runtime.h>
#include <hip/hip_bf16.h>

// Problem constants (from reference)
#define NN  256   // NUM_NODES
#define SS  4     // NUM_FSM_STATES
#define TT  3     // NUM_EDGE_TYPES
#define EE  2     // NUM_OUT_EDGES
#define VV  4     // NUM_VARIANTS
#define NTY 8     // NUM_NODE_TYPES
#define NAC 15    // n_actions = T*S + 3
#define CAP 48    // max in-degree capacity (Binom(256,0.05): mean 12.8, 48 is >10 sigma)

struct Edge { int j; float w; };

// flag==1 -> input buffers are bf16; flag==0 -> fp32
__device__ __forceinline__ float load_in(const void* base, int idx, int isbf16) {
    if (isbf16) return __bfloat162float(((const __hip_bfloat16*)base)[idx]);
    return ((const float*)base)[idx];
}

// ---------------------------------------------------------------------------
// K0: dtype detector. A true-fp32 adjacency is exactly {0.0,1.0}; bf16 bytes
// reinterpreted as fp32 fail that with probability ~1. One wave, 1024 words
// (4 KB, within bounds for either dtype interpretation).
__global__ void k_detect(const void* __restrict__ adj, int* __restrict__ flag) {
    const int lane = threadIdx.x;
    const float* a = (const float*)adj;
    int bad = 0;
#pragma unroll
    for (int c = 0; c < 16; c++) {
        float v = a[lane * 16 + c];
        if (!(v == 0.0f || v == 1.0f)) bad = 1;
    }
    unsigned long long b = __ballot(bad);
    if (lane == 0) flag[0] = (b != 0ULL) ? 1 : 0;
}

// ---------------------------------------------------------------------------
// K0b: convert variant_weights to fp32 in workspace (hot loop reads this).
__global__ void k_cvt_vw(const void* __restrict__ vw, const int* __restrict__ flag,
                         float* __restrict__ vw_f) {
    const int idx = blockIdx.x * blockDim.x + threadIdx.x;   // 262144 total
    const int f = flag[0];
    vw_f[idx] = load_in(vw, idx, f);
}

// ---------------------------------------------------------------------------
// K1: softmax of log_routing_params -> pol [V][NTY][S][NAC], 128 rows of 15
__global__ void k_pol(const void* __restrict__ lrp, const int* __restrict__ flag,
                      float* __restrict__ pol) {
    int r = threadIdx.x;
    if (r >= VV * NTY * SS) return;
    const int f = flag[0];
    float x[NAC];
    float m = -3.4e38f;
#pragma unroll
    for (int a = 0; a < NAC; a++) { x[a] = load_in(lrp, r * NAC + a, f); m = fmaxf(m, x[a]); }
    float s = 0.f;
#pragma unroll
    for (int a = 0; a < NAC; a++) { x[a] = __expf(x[a] - m); s += x[a]; }
    float inv = 1.f / s;
#pragma unroll
    for (int a = 0; a < NAC; a++) pol[r * NAC + a] = x[a] * inv;
}

// ---------------------------------------------------------------------------
// K2: inv_deg[t][j] = 1 / max(sum_k adj[t][j][k], 1).  One wave per row.
__global__ void k_deg(const void* __restrict__ adj, const int* __restrict__ flag,
                      float* __restrict__ inv_deg) {
    int row = blockIdx.x;           // t*NN + j
    int lane = threadIdx.x;         // 0..63
    const int f = flag[0];
    float s = 0.f;
    for (int k = lane; k < NN; k += 64) s += load_in(adj, row * NN + k, f);
#pragma unroll
    for (int off = 32; off > 0; off >>= 1) s += __shfl_down(s, off, 64);
    if (lane == 0) inv_deg[row] = 1.0f / fmaxf(s, 1.0f);
}

// ---------------------------------------------------------------------------
// K3: CSC build. edges laid out [t][slot][k] so lanes (k) stream coalesced.
__global__ void k_build(const void* __restrict__ adj, const int* __restrict__ flag,
                        const float* __restrict__ inv_deg,
                        int* __restrict__ counts, Edge* __restrict__ edges) {
    int t = blockIdx.x;
    int k = threadIdx.x;
    const int f = flag[0];
    int cnt = 0;
    for (int j = 0; j < NN; j++) {
        float a = load_in(adj, (t * NN + j) * NN + k, f);
        if (a != 0.f && cnt < CAP) {
            Edge ed; ed.j = j; ed.w = a * inv_deg[t * NN + j];
            edges[((size_t)t * CAP + cnt) * NN + k] = ed;
            cnt++;
        }
    }
    counts[t * NN + k] = cnt;
}

// ---------------------------------------------------------------------------
// K4: main automaton loop. One block per i; 512 threads = (e in {0,1}) x (col 0..255).
__global__ __launch_bounds__(512) void k_main(
    const float* __restrict__ vw_f,
    const int* __restrict__ node_types,
    const float* __restrict__ pol,
    const int* __restrict__ counts,
    const Edge* __restrict__ edges,
    const int* __restrict__ steps_p,
    const int* __restrict__ flag,
    void* __restrict__ out)
{
    const int i    = blockIdx.x;
    const int tid  = threadIdx.x;
    const int e    = tid >> 8;     // 0..1
    const int col  = tid & 255;    // node column this thread owns
    const int wave = tid >> 6;
    const int lane = tid & 63;
    const int steps = steps_p[0];

    // tmp[e][j][t*4+u], row padded 12->16 floats (64B stride: 2-way bank alias = free)
    __shared__ __align__(16) float tmp[EE * NN * 16];
    __shared__ float backp[8];

    // --- per-thread mixed policy for (i, col) ---
    const float4 wv4 = *(const float4*)(vw_f + ((size_t)i * NN + col) * VV);
    float wv[VV] = {wv4.x, wv4.y, wv4.z, wv4.w};
    const int ntj = node_types[col];
    float pm[SS][12], pacc[SS], pback[SS];
#pragma unroll
    for (int s = 0; s < SS; s++) {
        pacc[s] = 0.f; pback[s] = 0.f;
#pragma unroll
        for (int a = 0; a < 12; a++) pm[s][a] = 0.f;
    }
#pragma unroll
    for (int v = 0; v < VV; v++) {
        const float* pr = pol + (size_t)(v * NTY + ntj) * SS * NAC;
#pragma unroll
        for (int s = 0; s < SS; s++) {
            const float* p = pr + s * NAC;
#pragma unroll
            for (int a = 0; a < 12; a++) pm[s][a] = fmaf(wv[v], p[a], pm[s][a]);
            pacc[s]  = fmaf(wv[v], p[12], pacc[s]);
            pback[s] = fmaf(wv[v], p[13], pback[s]);
        }
    }

    // dist0[e,i,s,j] = (s==e)*(i==j)
    float D[SS];
#pragma unroll
    for (int s = 0; s < SS; s++) D[s] = (s == e && col == i) ? 1.0f : 0.0f;
    float acc = 0.f;

    // hoisted edge list metadata (constant across steps)
    int cnt_t[TT];
    const Edge* el_t[TT];
#pragma unroll
    for (int t = 0; t < TT; t++) {
        cnt_t[t] = counts[t * NN + col];
        el_t[t]  = edges + (size_t)t * CAP * NN + col;
    }

    float* myrow = &tmp[(e * NN + col) * 16];

    for (int step = 0; step < steps; step++) {
        // ---- phase A: accept/back + tmp[e,t,u,col] from old D ----
        float ad = D[0] * pacc[0];
        ad = fmaf(D[1], pacc[1], ad);
        ad = fmaf(D[2], pacc[2], ad);
        ad = fmaf(D[3], pacc[3], ad);
        acc += ad;
        float bj = D[0] * pback[0];
        bj = fmaf(D[1], pback[1], bj);
        bj = fmaf(D[2], pback[2], bj);
        bj = fmaf(D[3], pback[3], bj);

        float tv[12];
#pragma unroll
        for (int a = 0; a < 12; a++) {
            float x = D[0] * pm[0][a];
            x = fmaf(D[1], pm[1][a], x);
            x = fmaf(D[2], pm[2][a], x);
            x = fmaf(D[3], pm[3][a], x);
            tv[a] = x;
        }
        ((float4*)myrow)[0] = make_float4(tv[0], tv[1], tv[2],  tv[3]);
        ((float4*)myrow)[1] = make_float4(tv[4], tv[5], tv[6],  tv[7]);
        ((float4*)myrow)[2] = make_float4(tv[8], tv[9], tv[10], tv[11]);

        // back: reduce over j within this e-half (wave partials)
#pragma unroll
        for (int off = 32; off > 0; off >>= 1) bj += __shfl_down(bj, off, 64);
        if (lane == 0) backp[wave] = bj;
        __syncthreads();

        // ---- phase B: gather D'[u,col] over in-edges ----
        float Dn0 = 0.f, Dn1 = 0.f, Dn2 = 0.f, Dn3 = 0.f;
#pragma unroll
        for (int t = 0; t < TT; t++) {
            const int cnt = cnt_t[t];
            const Edge* el = el_t[t];
            const float* tb = &tmp[e * NN * 16 + t * 4];
            for (int c = 0; c < cnt; c++) {
                Edge ed = el[(size_t)c * NN];
                const float4 tv4 = *(const float4*)(tb + ed.j * 16);
                Dn0 = fmaf(tv4.x, ed.w, Dn0);
                Dn1 = fmaf(tv4.y, ed.w, Dn1);
                Dn2 = fmaf(tv4.z, ed.w, Dn2);
                Dn3 = fmaf(tv4.w, ed.w, Dn3);
            }
        }
        // restart: D'[e, s=e, j=i] += back[e]*0.999
        if (col == i) {
            float back = backp[e * 4 + 0] + backp[e * 4 + 1] + backp[e * 4 + 2] + backp[e * 4 + 3];
            if (e == 0) Dn0 = fmaf(back, 0.999f, Dn0);
            else        Dn1 = fmaf(back, 0.999f, Dn1);
        }
        __syncthreads();   // protect tmp + backp before next step overwrites
        D[0] = Dn0; D[1] = Dn1; D[2] = Dn2; D[3] = Dn3;
    }

    // final accept accumulation
    float ad = D[0] * pacc[0];
    ad = fmaf(D[1], pacc[1], ad);
    ad = fmaf(D[2], pacc[2], ad);
    ad = fmaf(D[3], pacc[3], ad);
    acc += ad;

    const size_t oidx = ((size_t)e * NN + i) * NN + col;
    if (flag[0]) ((__hip_bfloat16*)out)[oidx] = __float2bfloat16(acc);
    else         ((float*)out)[oidx] = acc;
}

// ---------------------------------------------------------------------------
extern "C" void kernel_launch(void* const* d_in, const int* in_sizes, int n_in,
                              void* d_out, int out_size, void* d_ws, size_t ws_size,
                              hipStream_t stream) {
    const void* vw   = d_in[0];            // (N,N,V)   fp32 or bf16
    const void* adj  = d_in[1];            // (T,N,N)   fp32 or bf16
    const void* lrp  = d_in[2];            // (V,NTY,S,NAC)
    const int* node_types = (const int*)d_in[3];  // (N,)
    const int* steps_p    = (const int*)d_in[4];  // scalar

    float* ws      = (float*)d_ws;
    float* pol     = ws;                    // 1920 f
    float* inv_deg = ws + 1920;             // 768 f
    int*   counts  = (int*)(ws + 2688);     // 768 i
    int*   flag    = (int*)(ws + 3456);     // 1 i (+15 pad)
    float* vw_f    = ws + 3472;             // 262144 f
    Edge*  edges   = (Edge*)(ws + 3472 + 262144); // 36864 * 8B = 294912 B
    // total ~= 1.36 MB of d_ws

    k_detect<<<1, 64, 0, stream>>>(adj, flag);
    k_cvt_vw<<<1024, 256, 0, stream>>>(vw, flag, vw_f);
    k_pol<<<1, 128, 0, stream>>>(lrp, flag, pol);
    k_deg<<<TT * NN, 64, 0, stream>>>(adj, flag, inv_deg);
    k_build<<<TT, NN, 0, stream>>>(adj, flag, inv_deg, counts, edges);
    k_main<<<NN, 512, 0, stream>>>(vw_f, node_types, pol, counts, edges, steps_p, flag, d_out);
}

// Round 3
// 443.695 us; speedup vs baseline: 1.1235x; 1.1235x over previous
//
#include <hip/hip_runtime.h>
#include <hip/hip_fp16.h>

// Problem constants (from reference)
#define NN   256   // NUM_NODES
#define SS   4     // NUM_FSM_STATES
#define TT   3     // NUM_EDGE_TYPES
#define VV   4     // NUM_VARIANTS
#define NTY  8     // NUM_NODE_TYPES
#define NAC  15    // n_actions = T*S + 3
#define CAPG 48    // max u32 pair-groups per col = 96 edges (flat deg ~Poi(38.4), 9+ sigma)
#define ROWH 20    // halves per tmp row (12 used + 8 pad) -> 40B stride, 16 bank classes
#define ZROW (256 * ROWH)   // dummy zero row (half offset) for odd-list padding

static __device__ __forceinline__ unsigned packh2(float a, float b) {
    __half2 h = __floats2half2_rn(a, b);
    return *(unsigned*)&h;
}

// ---------------------------------------------------------------------------
// Fused setup: blocks 0..767 = inv_deg rows, 768..771 = edge-list build,
// 772 = routing softmax. 64 threads each, all independent.
__global__ void k_setup(const float* __restrict__ adj,
                        const float* __restrict__ lrp,
                        float* __restrict__ inv_deg,
                        float* __restrict__ pol,
                        unsigned* __restrict__ epk,
                        int* __restrict__ gcnt) {
    const int b = blockIdx.x;
    const int lane = threadIdx.x;
    if (b < TT * NN) {
        // inv_deg[t][j] = 1/max(deg,1); one wave per row
        float s = 0.f;
        for (int k = lane; k < NN; k += 64) s += adj[(size_t)b * NN + k];
#pragma unroll
        for (int off = 32; off > 0; off >>= 1) s += __shfl_down(s, off, 64);
        if (lane == 0) inv_deg[b] = 1.0f / fmaxf(s, 1.0f);
    } else if (b < TT * NN + 4) {
        // flat edge list per col: u16 LDS offsets (j*ROWH + t*4), packed 2/u32
        const int col = (b - TT * NN) * 64 + lane;
        int cnt = 0; unsigned cur = 0;
        for (int t = 0; t < TT; t++)
            for (int j = 0; j < NN; j++) {
                float a = adj[((size_t)t * NN + j) * NN + col];
                if (a != 0.f) {
                    unsigned off = (unsigned)(j * ROWH + t * 4);
                    if (cnt & 1) { cur |= off << 16; if ((cnt >> 1) < CAPG) epk[(cnt >> 1) * NN + col] = cur; }
                    else cur = off;
                    cnt++;
                }
            }
        if (cnt & 1) { cur |= ((unsigned)ZROW) << 16; if ((cnt >> 1) < CAPG) epk[(cnt >> 1) * NN + col] = cur; cnt++; }
        int g = cnt >> 1;
        gcnt[col] = g > CAPG ? CAPG : g;
    } else {
        // softmax of log_routing_params -> pol, 128 rows of NAC
        for (int r = lane; r < VV * NTY * SS; r += 64) {
            float x[NAC]; float m = -3.4e38f;
#pragma unroll
            for (int a = 0; a < NAC; a++) { x[a] = lrp[r * NAC + a]; m = fmaxf(m, x[a]); }
            float ssum = 0.f;
#pragma unroll
            for (int a = 0; a < NAC; a++) { x[a] = __expf(x[a] - m); ssum += x[a]; }
            float inv = 1.f / ssum;
#pragma unroll
            for (int a = 0; a < NAC; a++) pol[r * NAC + a] = x[a] * inv;
        }
    }
}

// ---------------------------------------------------------------------------
// Main loop. Grid 512 = (e,i); block 512 threads = 2 subs x 256 cols.
// sub0 owns state D[s] + policy for its col; both subs split the edge gather.
__global__ __launch_bounds__(512, 4) void k_main(
    const float* __restrict__ vw,
    const int* __restrict__ node_types,
    const float* __restrict__ pol,
    const float* __restrict__ inv_deg,
    const unsigned* __restrict__ epk,
    const int* __restrict__ gcnt,
    const int* __restrict__ steps_p,
    float* __restrict__ out)
{
    const int i    = blockIdx.x & 255;
    const int e    = blockIdx.x >> 8;
    const int tid  = threadIdx.x;
    const int col  = tid & 255;
    const int sub  = tid >> 8;      // 0: state owner, 1: gather helper
    const int wv_  = tid >> 6;      // wave 0..7 (0..3 are sub0)
    const int lane = tid & 63;
    const int steps = steps_p[0];

    __shared__ __align__(16) __half tmp[ZROW + ROWH];   // 257 rows x 40B = 10.3 KB
    __shared__ __align__(16) float comb[NN][4];          // sub1 partials, 4 KB
    __shared__ float backp[2][4];                        // parity-buffered wave partials

    // zero the dummy pad row once
    if (tid < ROWH / 2) ((unsigned*)tmp)[ZROW / 2 + tid] = 0u;

    // --- per-col mixed policy, pre-scaled by inv_deg (sub0 only) ---
    float pmS[SS][12], pacc[SS], pback[SS], D[SS];
    float acc = 0.f;
    if (sub == 0) {
        const float4 w4 = *(const float4*)(vw + ((size_t)i * NN + col) * VV);
        float wvv[VV] = {w4.x, w4.y, w4.z, w4.w};
        const int ntj = node_types[col];
        float invd[TT];
#pragma unroll
        for (int t = 0; t < TT; t++) invd[t] = inv_deg[t * NN + col];
#pragma unroll
        for (int s = 0; s < SS; s++) {
            pacc[s] = 0.f; pback[s] = 0.f;
#pragma unroll
            for (int a = 0; a < 12; a++) pmS[s][a] = 0.f;
        }
#pragma unroll
        for (int v = 0; v < VV; v++) {
            const float* pr = pol + (size_t)(v * NTY + ntj) * SS * NAC;
#pragma unroll
            for (int s = 0; s < SS; s++) {
                const float* p = pr + s * NAC;
#pragma unroll
                for (int a = 0; a < 12; a++) pmS[s][a] = fmaf(wvv[v], p[a], pmS[s][a]);
                pacc[s]  = fmaf(wvv[v], p[12], pacc[s]);
                pback[s] = fmaf(wvv[v], p[13], pback[s]);
            }
        }
        // fold a_norm weight (inv_deg of OUR row) into the move coefficients
#pragma unroll
        for (int s = 0; s < SS; s++)
#pragma unroll
            for (int a = 0; a < 12; a++) pmS[s][a] *= invd[a >> 2];
#pragma unroll
        for (int s = 0; s < SS; s++) D[s] = (s == e && col == i) ? 1.0f : 0.0f;
    }

    // edge list split between the two subs
    const int g_all = gcnt[col];
    const int gh = (g_all + 1) >> 1;
    const int g0 = sub ? gh : 0;
    const int g1 = sub ? g_all : gh;
    __half* const myrow = tmp + col * ROWH;

    for (int step = 0; step < steps; step++) {
        // ---- phase A (sub0): accept/back + scaled tmp row ----
        if (sub == 0) {
            float ad = D[0] * pacc[0];
            ad = fmaf(D[1], pacc[1], ad); ad = fmaf(D[2], pacc[2], ad); ad = fmaf(D[3], pacc[3], ad);
            acc += ad;
            float bj = D[0] * pback[0];
            bj = fmaf(D[1], pback[1], bj); bj = fmaf(D[2], pback[2], bj); bj = fmaf(D[3], pback[3], bj);

            float tv[12];
#pragma unroll
            for (int a = 0; a < 12; a++) {
                float x = D[0] * pmS[0][a];
                x = fmaf(D[1], pmS[1][a], x);
                x = fmaf(D[2], pmS[2][a], x);
                x = fmaf(D[3], pmS[3][a], x);
                tv[a] = x;
            }
            uint2 w01; w01.x = packh2(tv[0], tv[1]);  w01.y = packh2(tv[2], tv[3]);
            uint2 w23; w23.x = packh2(tv[4], tv[5]);  w23.y = packh2(tv[6], tv[7]);
            uint2 w45; w45.x = packh2(tv[8], tv[9]);  w45.y = packh2(tv[10], tv[11]);
            *(uint2*)(myrow)     = w01;
            *(uint2*)(myrow + 4) = w23;
            *(uint2*)(myrow + 8) = w45;

#pragma unroll
            for (int off = 32; off > 0; off >>= 1) bj += __shfl_down(bj, off, 64);
            if (lane == 0) backp[step & 1][wv_] = bj;
        }
        __syncthreads();

        // ---- phase B (both subs): pure-sum gather of scaled rows ----
        float d0 = 0.f, d1 = 0.f, d2 = 0.f, d3 = 0.f;
        for (int g = g0; g < g1; g++) {
            unsigned pk = epk[g * NN + col];
            unsigned o0 = pk & 0xffffu, o1 = pk >> 16;
            uint2 q0 = *(const uint2*)(tmp + o0);
            uint2 q1 = *(const uint2*)(tmp + o1);
            float2 a0 = __half22float2(*(__half2*)&q0.x);
            float2 b0 = __half22float2(*(__half2*)&q0.y);
            float2 a1 = __half22float2(*(__half2*)&q1.x);
            float2 b1 = __half22float2(*(__half2*)&q1.y);
            d0 += a0.x + a1.x;
            d1 += a0.y + a1.y;
            d2 += b0.x + b1.x;
            d3 += b0.y + b1.y;
        }
        if (sub == 1) {
            comb[col][0] = d0; comb[col][1] = d1; comb[col][2] = d2; comb[col][3] = d3;
        }
        __syncthreads();

        // ---- combine + restart (sub0) ----
        if (sub == 0) {
            float4 c = *(const float4*)comb[col];
            d0 += c.x; d1 += c.y; d2 += c.z; d3 += c.w;
            const float* bp = backp[step & 1];
            float back = bp[0] + bp[1] + bp[2] + bp[3];
            if (col == i) {
                if (e == 0) d0 = fmaf(back, 0.999f, d0);
                else        d1 = fmaf(back, 0.999f, d1);
            }
            D[0] = d0; D[1] = d1; D[2] = d2; D[3] = d3;
        }
    }

    if (sub == 0) {
        float ad = D[0] * pacc[0];
        ad = fmaf(D[1], pacc[1], ad); ad = fmaf(D[2], pacc[2], ad); ad = fmaf(D[3], pacc[3], ad);
        acc += ad;
        out[((size_t)e * NN + i) * NN + col] = acc;
    }
}

// ---------------------------------------------------------------------------
extern "C" void kernel_launch(void* const* d_in, const int* in_sizes, int n_in,
                              void* d_out, int out_size, void* d_ws, size_t ws_size,
                              hipStream_t stream) {
    const float* vw  = (const float*)d_in[0];   // (N,N,V) fp32
    const float* adj = (const float*)d_in[1];   // (T,N,N) fp32 {0,1}
    const float* lrp = (const float*)d_in[2];   // (V,NTY,S,NAC) fp32
    const int* node_types = (const int*)d_in[3];
    const int* steps_p    = (const int*)d_in[4];

    float* ws       = (float*)d_ws;
    float* pol      = ws;                        // 1920 f
    float* inv_deg  = ws + 1920;                 // 768 f
    int*   gcnt     = (int*)(ws + 2688);         // 256 i
    unsigned* epk   = (unsigned*)(ws + 2944);    // CAPG*NN u32 = 49 KB

    k_setup<<<TT * NN + 5, 64, 0, stream>>>(adj, lrp, inv_deg, pol, epk, gcnt);
    k_main<<<2 * NN, 512, 0, stream>>>(vw, node_types, pol, inv_deg, epk, gcnt,
                                       steps_p, (float*)d_out);
}

// Round 4
// 210.307 us; speedup vs baseline: 2.3704x; 2.1097x over previous
//
#include <hip/hip_runtime.h>
#include <hip/hip_fp16.h>

// Problem constants
#define NN   256   // NUM_NODES
#define SS   4     // NUM_FSM_STATES
#define TT   3     // NUM_EDGE_TYPES
#define VV   4     // NUM_VARIANTS
#define NTY  8     // NUM_NODE_TYPES
#define NAC  15    // n_actions = T*S + 3
#define CAPG 48    // max packed pair-groups per col (96 edges; deg~Poi(38.4), 9+ sigma)
#define ROWB 40    // bytes per tmp row (12 halves used + pad) -> word stride 10
#define ZROWB (NN * ROWB)      // zero pad row byte offset = 10240 (fits u16)
#define BUFB  (ZROWB + ROWB)   // bytes per tmp buffer = 10280 (8B aligned)
#define ZPK   ((unsigned)ZROWB | ((unsigned)ZROWB << 16))

typedef _Float16 h2v __attribute__((ext_vector_type(2)));

#if defined(__has_builtin)
#if __has_builtin(__builtin_amdgcn_fdot2)
#define HAVE_FDOT2 1
#endif
#endif

static __device__ __forceinline__ unsigned ph2(float a, float b) {
    union { __half2 h; unsigned u; } c;
    c.h = __floats2half2_rn(a, b);
    return c.u;
}
static __device__ __forceinline__ h2v bch2(unsigned u) {
    union { unsigned u; h2v h; } c; c.u = u; return c.h;
}
static __device__ __forceinline__ float2 h2f2(unsigned u) {
    union { unsigned u; __half2 h; } c; c.u = u; return __half22float2(c.h);
}

// ---------------------------------------------------------------------------
// Setup, fully parallel: blocks 0..767 = inv_deg row sums (coalesced),
// 768..1023 = per-col edge build (LDS atomic compaction, order-free),
// 1024 = routing softmax. 256 threads each.
__global__ void k_setup(const float* __restrict__ adj,
                        const float* __restrict__ lrp,
                        float* __restrict__ inv_deg,
                        float* __restrict__ pol,
                        unsigned* __restrict__ epk,
                        int* __restrict__ gcnt) {
    __shared__ float wsum[4];
    __shared__ int cnt;
    __shared__ unsigned short offs[CAPG * 2 + 2];

    const int b = blockIdx.x;
    const int tid = threadIdx.x;

    if (b < TT * NN) {
        // degree of row b: 256 coalesced loads, wave+LDS reduce
        float s = adj[(size_t)b * NN + tid];
#pragma unroll
        for (int off = 32; off > 0; off >>= 1) s += __shfl_down(s, off, 64);
        if ((tid & 63) == 0) wsum[tid >> 6] = s;
        __syncthreads();
        if (tid == 0)
            inv_deg[b] = 1.0f / fmaxf(wsum[0] + wsum[1] + wsum[2] + wsum[3], 1.0f);
    } else if (b < TT * NN + NN) {
        // edge list for column col: thread j tests (t,j,col) for t=0..2
        const int col = b - TT * NN;
        if (tid == 0) cnt = 0;
        __syncthreads();
#pragma unroll
        for (int t = 0; t < TT; t++) {
            float a = adj[((size_t)t * NN + tid) * NN + col];
            if (a != 0.f) {
                int idx = atomicAdd(&cnt, 1);
                if (idx < CAPG * 2) offs[idx] = (unsigned short)(tid * ROWB + t * 8);
            }
        }
        __syncthreads();
        int c = cnt; if (c > CAPG * 2) c = CAPG * 2;
        if (tid == 0 && (c & 1)) offs[c] = (unsigned short)ZROWB;   // pad odd
        __syncthreads();
        const int g = (c + 1) >> 1;
        for (int gg = tid; gg < g; gg += blockDim.x)
            epk[gg * NN + col] = (unsigned)offs[2 * gg] | ((unsigned)offs[2 * gg + 1] << 16);
        if (tid == 0) gcnt[col] = g;
    } else {
        // softmax of log_routing_params (128 rows of NAC)
        if (tid < VV * NTY * SS) {
            float x[NAC]; float m = -3.4e38f;
#pragma unroll
            for (int a = 0; a < NAC; a++) { x[a] = lrp[tid * NAC + a]; m = fmaxf(m, x[a]); }
            float ssum = 0.f;
#pragma unroll
            for (int a = 0; a < NAC; a++) { x[a] = __expf(x[a] - m); ssum += x[a]; }
            float inv = 1.f / ssum;
#pragma unroll
            for (int a = 0; a < NAC; a++) pol[tid * NAC + a] = x[a] * inv;
        }
    }
}

// ---------------------------------------------------------------------------
// Main loop: grid 512 = (e,i); block 256 threads = one col each; 4 waves.
// Single barrier per step via parity-double-buffered tmp.
__global__ __launch_bounds__(256, 2) void k_main(
    const float* __restrict__ vw,
    const int* __restrict__ node_types,
    const float* __restrict__ pol,
    const float* __restrict__ inv_deg,
    const unsigned* __restrict__ epk,
    const int* __restrict__ gcnt,
    const int* __restrict__ steps_p,
    float* __restrict__ out)
{
    const int i    = blockIdx.x & 255;
    const int e    = blockIdx.x >> 8;
    const int col  = threadIdx.x;
    const int wv   = col >> 6;
    const int lane = col & 63;
    const int steps = steps_p[0];

    __shared__ __align__(16) char tmpb[2 * BUFB];   // 20.6 KB
    __shared__ float backp[2][4];

    // zero both buffers' pad row (10 words each)
    if (col < 20) {
        int pb = col / 10, w = col % 10;
        ((unsigned*)(tmpb + pb * BUFB + ZROWB))[w] = 0u;
    }

    // --- per-col mixed policy, pre-scaled by inv_deg ---
    const float4 w4 = *(const float4*)(vw + ((size_t)i * NN + col) * VV);
    const float wvv[VV] = {w4.x, w4.y, w4.z, w4.w};
    const int ntj = node_types[col];
    float pmS[SS][12], pacc[SS], pback[SS];
#pragma unroll
    for (int s = 0; s < SS; s++) {
        pacc[s] = 0.f; pback[s] = 0.f;
#pragma unroll
        for (int a = 0; a < 12; a++) pmS[s][a] = 0.f;
    }
#pragma unroll
    for (int v = 0; v < VV; v++) {
        const float* pr = pol + (size_t)(v * NTY + ntj) * SS * NAC;
#pragma unroll
        for (int s = 0; s < SS; s++) {
            const float* p = pr + s * NAC;
#pragma unroll
            for (int a = 0; a < 12; a++) pmS[s][a] = fmaf(wvv[v], p[a], pmS[s][a]);
            pacc[s]  = fmaf(wvv[v], p[12], pacc[s]);
            pback[s] = fmaf(wvv[v], p[13], pback[s]);
        }
    }
    {
        float invd[TT];
#pragma unroll
        for (int t = 0; t < TT; t++) invd[t] = inv_deg[t * NN + col];
#pragma unroll
        for (int s = 0; s < SS; s++)
#pragma unroll
            for (int a = 0; a < 12; a++) pmS[s][a] *= invd[a >> 2];
    }

    float D0 = (0 == e && col == i) ? 1.f : 0.f;
    float D1 = (1 == e && col == i) ? 1.f : 0.f;
    float D2 = 0.f, D3 = 0.f;
    float acc = 0.f;

    // wave-uniform gather trip count (tail lanes read the zero row: broadcast)
    const int g_all = gcnt[col];
    int gmax = g_all;
#pragma unroll
    for (int off = 32; off > 0; off >>= 1) {
        int o = __shfl_xor(gmax, off, 64);
        gmax = o > gmax ? o : gmax;
    }

    const h2v S10 = {(_Float16)1.0f, (_Float16)0.0f};
    const h2v S01 = {(_Float16)0.0f, (_Float16)1.0f};
    char* const myrow0 = tmpb + col * ROWB;

    for (int step = 0; step < steps; step++) {
        const int par = step & 1;
        char* const buf = tmpb + par * BUFB;

        // ---- phase A: accept/back + scaled tmp row into buf[par] ----
        float ad = D0 * pacc[0];
        ad = fmaf(D1, pacc[1], ad); ad = fmaf(D2, pacc[2], ad); ad = fmaf(D3, pacc[3], ad);
        acc += ad;
        float bj = D0 * pback[0];
        bj = fmaf(D1, pback[1], bj); bj = fmaf(D2, pback[2], bj); bj = fmaf(D3, pback[3], bj);

        float tv[12];
#pragma unroll
        for (int a = 0; a < 12; a++) {
            float x = D0 * pmS[0][a];
            x = fmaf(D1, pmS[1][a], x);
            x = fmaf(D2, pmS[2][a], x);
            x = fmaf(D3, pmS[3][a], x);
            tv[a] = x;
        }
        char* const myrow = myrow0 + par * BUFB;
        uint2 wA; wA.x = ph2(tv[0], tv[1]);  wA.y = ph2(tv[2],  tv[3]);
        uint2 wB; wB.x = ph2(tv[4], tv[5]);  wB.y = ph2(tv[6],  tv[7]);
        uint2 wC; wC.x = ph2(tv[8], tv[9]);  wC.y = ph2(tv[10], tv[11]);
        *(uint2*)(myrow)      = wA;
        *(uint2*)(myrow + 8)  = wB;
        *(uint2*)(myrow + 16) = wC;

#pragma unroll
        for (int off = 32; off > 0; off >>= 1) bj += __shfl_down(bj, off, 64);
        if (lane == 0) backp[par][wv] = bj;

        __syncthreads();   // the ONLY barrier per step

        // ---- phase B: gather over in-edges from buf[par] ----
        float d0 = 0.f, d1 = 0.f, d2 = 0.f, d3 = 0.f;
#pragma unroll 4
        for (int g = 0; g < gmax; g++) {
            unsigned pk = epk[g * NN + col];
            pk = (g < g_all) ? pk : ZPK;
            const uint2 q0 = *(const uint2*)(buf + (pk & 0xffffu));
            const uint2 q1 = *(const uint2*)(buf + (pk >> 16));
#ifdef HAVE_FDOT2
            d0 = __builtin_amdgcn_fdot2(bch2(q0.x), S10, d0, false);
            d1 = __builtin_amdgcn_fdot2(bch2(q0.x), S01, d1, false);
            d2 = __builtin_amdgcn_fdot2(bch2(q0.y), S10, d2, false);
            d3 = __builtin_amdgcn_fdot2(bch2(q0.y), S01, d3, false);
            d0 = __builtin_amdgcn_fdot2(bch2(q1.x), S10, d0, false);
            d1 = __builtin_amdgcn_fdot2(bch2(q1.x), S01, d1, false);
            d2 = __builtin_amdgcn_fdot2(bch2(q1.y), S10, d2, false);
            d3 = __builtin_amdgcn_fdot2(bch2(q1.y), S01, d3, false);
#else
            float2 f0 = h2f2(q0.x), f1 = h2f2(q0.y), f2 = h2f2(q1.x), f3 = h2f2(q1.y);
            d0 += f0.x + f2.x; d1 += f0.y + f2.y;
            d2 += f1.x + f3.x; d3 += f1.y + f3.y;
#endif
        }

        // ---- combine + restart ----
        if (col == i) {
            const float* bp = backp[par];
            float back = bp[0] + bp[1] + bp[2] + bp[3];
            if (e == 0) d0 = fmaf(back, 0.999f, d0);
            else        d1 = fmaf(back, 0.999f, d1);
        }
        D0 = d0; D1 = d1; D2 = d2; D3 = d3;
    }

    float ad = D0 * pacc[0];
    ad = fmaf(D1, pacc[1], ad); ad = fmaf(D2, pacc[2], ad); ad = fmaf(D3, pacc[3], ad);
    acc += ad;
    out[((size_t)e * NN + i) * NN + col] = acc;
}

// ---------------------------------------------------------------------------
extern "C" void kernel_launch(void* const* d_in, const int* in_sizes, int n_in,
                              void* d_out, int out_size, void* d_ws, size_t ws_size,
                              hipStream_t stream) {
    const float* vw  = (const float*)d_in[0];   // (N,N,V) fp32
    const float* adj = (const float*)d_in[1];   // (T,N,N) fp32 {0,1}
    const float* lrp = (const float*)d_in[2];   // (V,NTY,S,NAC) fp32
    const int* node_types = (const int*)d_in[3];
    const int* steps_p    = (const int*)d_in[4];

    float* ws       = (float*)d_ws;
    float* pol      = ws;                        // 1920 f
    float* inv_deg  = ws + 1920;                 // 768 f
    int*   gcnt     = (int*)(ws + 2688);         // 256 i
    unsigned* epk   = (unsigned*)(ws + 2944);    // CAPG*NN u32 = 48 KB

    k_setup<<<TT * NN + NN + 1, 256, 0, stream>>>(adj, lrp, inv_deg, pol, epk, gcnt);
    k_main<<<2 * NN, 256, 0, stream>>>(vw, node_types, pol, inv_deg, epk, gcnt,
                                       steps_p, (float*)d_out);
}